// Round 12
// baseline (171.804 us; speedup 1.0000x reference)
//
#include <hip/hip_runtime.h>
#include <hip/hip_bf16.h>

#define NN 8192
#define DD 128

typedef __attribute__((ext_vector_type(4))) float f32x4;
typedef __attribute__((ext_vector_type(16))) float f32x16;
typedef __attribute__((ext_vector_type(8))) short bf16x8;
typedef __attribute__((ext_vector_type(4))) short s16x4;

__device__ __forceinline__ short f2bf(float f) {
  __hip_bfloat16 h = __float2bfloat16(f);
  return __builtin_bit_cast(short, h);
}
__device__ __forceinline__ float bf2f(short s) {
  unsigned u = ((unsigned)(unsigned short)s) << 16;
  return __builtin_bit_cast(float, u);
}

// async global->LDS, 16B/lane. AUX: 0 = cached, 2 = NT (no-allocate).
template <int AUX>
__device__ __forceinline__ void async_copy16(void* lds, const void* g) {
  __builtin_amdgcn_global_load_lds(
      (const __attribute__((address_space(1))) void*)g,
      (__attribute__((address_space(3))) void*)lds, 16, 0, AUX);
}

// ---------------------------------------------------------------------------
// Kernel 1: yT[n][k] = sum_d x[k][d] * W[d][n]   (bf16, transposed)
// ---------------------------------------------------------------------------
__global__ __launch_bounds__(256) void xw_kernel(
    const float* __restrict__ x, const float* __restrict__ W,
    short* __restrict__ yT)
{
  __shared__ float xs[32][129];
  __shared__ float Ws[128 * 128];
  const int t  = threadIdx.x;
  const int k0 = blockIdx.x * 32;

  #pragma unroll
  for (int i = 0; i < 16; ++i) {
    int idx = (i * 256 + t) * 4;
    *(f32x4*)&Ws[idx] = *(const f32x4*)(W + idx);
  }
  #pragma unroll
  for (int i = 0; i < 4; ++i) {
    int idx = i * 256 + t;
    int row = idx >> 5;
    int c4  = (idx & 31) * 4;
    f32x4 v = *(const f32x4*)(x + (size_t)(k0 + row) * DD + c4);
    xs[row][c4 + 0] = v[0]; xs[row][c4 + 1] = v[1];
    xs[row][c4 + 2] = v[2]; xs[row][c4 + 3] = v[3];
  }
  __syncthreads();

  const int kl = t & 31;
  const int g  = t >> 5;
  float acc[16];
  #pragma unroll
  for (int j = 0; j < 16; ++j) acc[j] = 0.f;

  for (int d = 0; d < 128; ++d) {
    float xv = xs[kl][d];
    const float* wr = &Ws[d * 128 + g * 16];
    f32x4 w0 = *(const f32x4*)(wr);
    f32x4 w1 = *(const f32x4*)(wr + 4);
    f32x4 w2 = *(const f32x4*)(wr + 8);
    f32x4 w3 = *(const f32x4*)(wr + 12);
    #pragma unroll
    for (int j = 0; j < 4; ++j) {
      acc[j]      += xv * w0[j];
      acc[4 + j]  += xv * w1[j];
      acc[8 + j]  += xv * w2[j];
      acc[12 + j] += xv * w3[j];
    }
  }
  #pragma unroll
  for (int j = 0; j < 16; ++j) {
    int n = g * 16 + j;
    yT[(size_t)n * NN + k0 + kl] = f2bf(acc[j]);
  }
}

// ---------------------------------------------------------------------------
// Kernel 2 == R11 structure exactly (85.4us baseline), ONE change:
// the cached/NT A-policy moves from per-mg-band to per-K-step inside EVERY
// block: steps = 6,7 (mod 8) stream NT (64MB), the rest cached (192MB,
// stable L3-resident across replays; + ~20MB other < 256MB L3).
// Every CU now issues cached and NT reads concurrently all run long ->
// directly probes whether L3-hit and HBM read paths have separate capacity
// (time collapses) or share one ~17GB/s/CU read cap (exact null).
// Policy is positional -> identical across graph replays. Compile-time AUX
// via fully-unrolled 8-step inner loop (prefetch step s+2: NT when u=4,5).
// ---------------------------------------------------------------------------
__global__ __launch_bounds__(512, 4) void gcn_main(
    const float* __restrict__ A, const short* __restrict__ yT,
    short* __restrict__ part, float* __restrict__ degpart)
{
  __shared__ float Abuf[2][256 * 32];   // 2 x 32 KB
  __shared__ short Ybuf[2][128 * 32];   // 2 x  8 KB

  const int tid = threadIdx.x;
  const int l   = tid & 63;
  const int w   = tid >> 6;            // wave 0..7
  const int ks  = blockIdx.x & 7;      // k-slice == XCD id
  const int mg  = blockIdx.x >> 3;     // 0..31
  const int R0  = mg * 256;
  const int kb  = ks * 1024;
  const int l31 = l & 31;
  const int hi  = l >> 5;
  const int wbase = w * 32;

  // staging sources (pre-swizzled)
  const int a_rin  = l >> 3;
  const int a_slot = l & 7;
  const float* gA[4];
  #pragma unroll
  for (int i = 0; i < 4; ++i) {
    const int r = wbase + 8 * i + a_rin;
    gA[i] = A + (size_t)(R0 + r) * NN + kb + ((a_slot ^ (r & 7)) << 2);
  }
  const int y_row = w * 16 + (l >> 2);
  const short* gY = yT + (size_t)y_row * NN + kb + (((l & 3) ^ (y_row & 3)) << 3);

  // read-side offsets
  const int arx = l31 & 7;
  int aoff[2][2];
  #pragma unroll
  for (int j = 0; j < 2; ++j)
    #pragma unroll
    for (int q = 0; q < 2; ++q)
      aoff[j][q] = (wbase + l31) * 32 + (((4 * j + 2 * hi + q) ^ arx) << 2);
  int yoff[4][2];
  #pragma unroll
  for (int f = 0; f < 4; ++f)
    #pragma unroll
    for (int j = 0; j < 2; ++j)
      yoff[f][j] = (f * 32 + l31) * 32 + (((2 * j + hi) ^ (l31 & 3)) << 3);

  f32x16 acc[4];
  #pragma unroll
  for (int f = 0; f < 4; ++f) acc[f] = (f32x16)0.f;
  float deg = 0.f;

#define STAGE(AUX, buf, step) do {                                          \
    const int _k = (step) * 32;                                             \
    _Pragma("unroll")                                                       \
    for (int _i = 0; _i < 4; ++_i)                                          \
      async_copy16<AUX>(&Abuf[buf][(wbase + 8 * _i) * 32], gA[_i] + _k);    \
    async_copy16<0>(&Ybuf[buf][w * 512], gY + _k);                          \
  } while (0)

  STAGE(0, 0, 0);   // step 0 (s&7 == 0 -> cached)
  STAGE(0, 1, 1);   // step 1 (cached)

  for (int sb = 0; sb < 32; sb += 8) {
    #pragma unroll
    for (int u = 0; u < 8; ++u) {
      const int s = sb + u;

      __builtin_amdgcn_sched_barrier(0);
      if (s < 31) asm volatile("s_waitcnt vmcnt(5)" ::: "memory");
      else        asm volatile("s_waitcnt vmcnt(0)" ::: "memory");
      __builtin_amdgcn_sched_barrier(0);
      __builtin_amdgcn_s_barrier();
      __builtin_amdgcn_sched_barrier(0);

      const float* Ab = &Abuf[s & 1][0];
      const short* Yb = &Ybuf[s & 1][0];

      #pragma unroll
      for (int j = 0; j < 2; ++j) {
        f32x4 a0 = *(const f32x4*)&Ab[aoff[j][0]];
        f32x4 a1 = *(const f32x4*)&Ab[aoff[j][1]];

        deg += (a0[0] + a0[1]) + (a0[2] + a0[3])
             + (a1[0] + a1[1]) + (a1[2] + a1[3]);

        bf16x8 a;
        #pragma unroll
        for (int e = 0; e < 4; ++e) { a[e] = f2bf(a0[e]); a[4 + e] = f2bf(a1[e]); }

        #pragma unroll
        for (int f = 0; f < 4; ++f) {
          bf16x8 b = *(const bf16x8*)&Yb[yoff[f][j]];
          acc[f] = __builtin_amdgcn_mfma_f32_32x32x16_bf16(a, b, acc[f], 0, 0, 0);
        }
      }

      __builtin_amdgcn_sched_barrier(0);
      __builtin_amdgcn_s_barrier();
      __builtin_amdgcn_sched_barrier(0);

      // prefetch step s+2; policy by (s+2)&7 = (u+2)&7: NT for u==4,5
      if (s + 2 < 32) {
        if (u == 4 || u == 5) STAGE(2, s & 1, s + 2);   // NT  (steps 6,7 mod 8)
        else                  STAGE(0, s & 1, s + 2);   // cached
      }
    }
  }
#undef STAGE

  deg += __shfl_xor(deg, 32);
  if (l < 32)
    degpart[(size_t)ks * NN + R0 + wbase + l] = deg;

  short* pb = part + (size_t)ks * NN * DD + (size_t)(R0 + wbase) * DD;
  #pragma unroll
  for (int f = 0; f < 4; ++f)
    #pragma unroll
    for (int r = 0; r < 16; ++r) {
      const int row = (r & 3) + 8 * (r >> 2) + 4 * hi;
      __builtin_nontemporal_store(f2bf(acc[f][r]),
          pb + (size_t)row * DD + f * 32 + l31);
    }
}

// ---------------------------------------------------------------------------
// Kernel 3: out[m][n] = (sum_ks part[ks][m][n]) / (sum_ks degpart[ks][m])
// ---------------------------------------------------------------------------
__global__ __launch_bounds__(256) void reduce_kernel(
    const short* __restrict__ part, const float* __restrict__ degpart,
    float* __restrict__ out)
{
  const int idx = blockIdx.x * 256 + threadIdx.x;
  const int m   = idx >> 5;
  const int c4  = (idx & 31) * 4;

  float s0 = 0.f, s1 = 0.f, s2 = 0.f, s3 = 0.f, d = 0.f;
  #pragma unroll
  for (int ks = 0; ks < 8; ++ks) {
    s16x4 v = *(const s16x4*)(part + (size_t)ks * NN * DD + (size_t)m * DD + c4);
    s0 += bf2f(v[0]); s1 += bf2f(v[1]); s2 += bf2f(v[2]); s3 += bf2f(v[3]);
    d += degpart[(size_t)ks * NN + m];
  }
  f32x4 r;
  r[0] = s0 / d; r[1] = s1 / d; r[2] = s2 / d; r[3] = s3 / d;
  *(f32x4*)(out + (size_t)m * DD + c4) = r;
}

extern "C" void kernel_launch(void* const* d_in, const int* in_sizes, int n_in,
                              void* d_out, int out_size, void* d_ws, size_t ws_size,
                              hipStream_t stream) {
  const float* x = (const float*)d_in[0];   // [8192,128] fp32
  const float* A = (const float*)d_in[1];   // [8192,8192] fp32
  const float* W = (const float*)d_in[2];   // [128,128] fp32
  float* out = (float*)d_out;               // [8192,128] fp32

  char* ws = (char*)d_ws;
  short* yT      = (short*)ws;                              // 2 MB  bf16 [128][8192]
  short* part    = (short*)(ws + (2u << 20));               // 16 MB bf16 [8][8192][128]
  float* degpart = (float*)(ws + (2u << 20) + (16u << 20)); // 256 KB fp32 [8][8192]

  xw_kernel<<<256, 256, 0, stream>>>(x, W, yT);
  gcn_main<<<256, 512, 0, stream>>>(A, yT, part, degpart);
  reduce_kernel<<<1024, 256, 0, stream>>>(part, degpart, out);
}

// Round 13
// 171.495 us; speedup vs baseline: 1.0018x; 1.0018x over previous
//
#include <hip/hip_runtime.h>
#include <hip/hip_bf16.h>

#define NN 8192
#define DD 128

typedef __attribute__((ext_vector_type(4))) float f32x4;
typedef __attribute__((ext_vector_type(16))) float f32x16;
typedef __attribute__((ext_vector_type(8))) short bf16x8;

__device__ __forceinline__ short f2bf(float f) {
  __hip_bfloat16 h = __float2bfloat16(f);
  return __builtin_bit_cast(short, h);
}
__device__ __forceinline__ float bf2f(short s) {
  unsigned u = ((unsigned)(unsigned short)s) << 16;
  return __builtin_bit_cast(float, u);
}

// async global->LDS, 16B/lane. AUX: 0 = cached, 2 = NT (no-allocate).
template <int AUX>
__device__ __forceinline__ void async_copy16(void* lds, const void* g) {
  __builtin_amdgcn_global_load_lds(
      (const __attribute__((address_space(1))) void*)g,
      (__attribute__((address_space(3))) void*)lds, 16, 0, AUX);
}

// ---------------------------------------------------------------------------
// Kernel 1: yT[n][k] = sum_d x[k][d] * W[d][n]   (bf16, transposed)
// ---------------------------------------------------------------------------
__global__ __launch_bounds__(256) void xw_kernel(
    const float* __restrict__ x, const float* __restrict__ W,
    short* __restrict__ yT)
{
  __shared__ float xs[32][129];
  __shared__ float Ws[128 * 128];
  const int t  = threadIdx.x;
  const int k0 = blockIdx.x * 32;

  #pragma unroll
  for (int i = 0; i < 16; ++i) {
    int idx = (i * 256 + t) * 4;
    *(f32x4*)&Ws[idx] = *(const f32x4*)(W + idx);
  }
  #pragma unroll
  for (int i = 0; i < 4; ++i) {
    int idx = i * 256 + t;
    int row = idx >> 5;
    int c4  = (idx & 31) * 4;
    f32x4 v = *(const f32x4*)(x + (size_t)(k0 + row) * DD + c4);
    xs[row][c4 + 0] = v[0]; xs[row][c4 + 1] = v[1];
    xs[row][c4 + 2] = v[2]; xs[row][c4 + 3] = v[3];
  }
  __syncthreads();

  const int kl = t & 31;
  const int g  = t >> 5;
  float acc[16];
  #pragma unroll
  for (int j = 0; j < 16; ++j) acc[j] = 0.f;

  for (int d = 0; d < 128; ++d) {
    float xv = xs[kl][d];
    const float* wr = &Ws[d * 128 + g * 16];
    f32x4 w0 = *(const f32x4*)(wr);
    f32x4 w1 = *(const f32x4*)(wr + 4);
    f32x4 w2 = *(const f32x4*)(wr + 8);
    f32x4 w3 = *(const f32x4*)(wr + 12);
    #pragma unroll
    for (int j = 0; j < 4; ++j) {
      acc[j]      += xv * w0[j];
      acc[4 + j]  += xv * w1[j];
      acc[8 + j]  += xv * w2[j];
      acc[12 + j] += xv * w3[j];
    }
  }
  #pragma unroll
  for (int j = 0; j < 16; ++j) {
    int n = g * 16 + j;
    yT[(size_t)n * NN + k0 + kl] = f2bf(acc[j]);
  }
}

// ---------------------------------------------------------------------------
// Kernel 2 = R11's gcn (85.4us config: NT on odd mg bands) + FUSED final
// reduction. The 8 ks-blocks of an mg are co-resident by construction
// (256 blocks, LDS 80KB -> capacity 2/CU*256 = 512 >= 256), so after
// storing part tiles each block release-fences (threadfence = L2 wbl2),
// atomicAdd's a per-mg counter, spins to 8, acquire-fences (inv stale
// lines -- required: replay reuses buffers), then finalizes its OWN
// 32-row chunk: sum 8 slices + divide by total degree. No reduce kernel,
// no serial tail (finish work spread over all 256 CUs).
// ---------------------------------------------------------------------------
template <int ANT>
__device__ __forceinline__ void gcn_body(
    const float* __restrict__ A, const short* __restrict__ yT,
    short* __restrict__ part, float* __restrict__ degpart,
    float* __restrict__ out, unsigned* __restrict__ cnt,
    float (&Abuf)[2][256 * 32], short (&Ybuf)[2][128 * 32])
{
  const int tid = threadIdx.x;
  const int l   = tid & 63;
  const int w   = tid >> 6;            // wave 0..7
  const int ks  = blockIdx.x & 7;      // k-slice == XCD id
  const int mg  = blockIdx.x >> 3;     // 0..31
  const int R0  = mg * 256;
  const int kb  = ks * 1024;
  const int l31 = l & 31;
  const int hi  = l >> 5;
  const int wbase = w * 32;

  // staging sources (pre-swizzled)
  const int a_rin  = l >> 3;
  const int a_slot = l & 7;
  const float* gA[4];
  #pragma unroll
  for (int i = 0; i < 4; ++i) {
    const int r = wbase + 8 * i + a_rin;
    gA[i] = A + (size_t)(R0 + r) * NN + kb + ((a_slot ^ (r & 7)) << 2);
  }
  const int y_row = w * 16 + (l >> 2);
  const short* gY = yT + (size_t)y_row * NN + kb + (((l & 3) ^ (y_row & 3)) << 3);

  // read-side offsets
  const int arx = l31 & 7;
  int aoff[2][2];
  #pragma unroll
  for (int j = 0; j < 2; ++j)
    #pragma unroll
    for (int q = 0; q < 2; ++q)
      aoff[j][q] = (wbase + l31) * 32 + (((4 * j + 2 * hi + q) ^ arx) << 2);
  int yoff[4][2];
  #pragma unroll
  for (int f = 0; f < 4; ++f)
    #pragma unroll
    for (int j = 0; j < 2; ++j)
      yoff[f][j] = (f * 32 + l31) * 32 + (((2 * j + hi) ^ (l31 & 3)) << 3);

  f32x16 acc[4];
  #pragma unroll
  for (int f = 0; f < 4; ++f) acc[f] = (f32x16)0.f;
  float deg = 0.f;

#define STAGE(buf, step) do {                                              \
    const int _k = (step) * 32;                                            \
    _Pragma("unroll")                                                      \
    for (int _i = 0; _i < 4; ++_i)                                         \
      async_copy16<ANT>(&Abuf[buf][(wbase + 8 * _i) * 32], gA[_i] + _k);   \
    async_copy16<0>(&Ybuf[buf][w * 512], gY + _k);                         \
  } while (0)

  STAGE(0, 0);
  STAGE(1, 1);

  for (int s = 0; s < 32; ++s) {
    __builtin_amdgcn_sched_barrier(0);
    if (s < 31) asm volatile("s_waitcnt vmcnt(5)" ::: "memory");
    else        asm volatile("s_waitcnt vmcnt(0)" ::: "memory");
    __builtin_amdgcn_sched_barrier(0);
    __builtin_amdgcn_s_barrier();
    __builtin_amdgcn_sched_barrier(0);

    const float* Ab = &Abuf[s & 1][0];
    const short* Yb = &Ybuf[s & 1][0];

    #pragma unroll
    for (int j = 0; j < 2; ++j) {
      f32x4 a0 = *(const f32x4*)&Ab[aoff[j][0]];
      f32x4 a1 = *(const f32x4*)&Ab[aoff[j][1]];

      deg += (a0[0] + a0[1]) + (a0[2] + a0[3])
           + (a1[0] + a1[1]) + (a1[2] + a1[3]);

      bf16x8 a;
      #pragma unroll
      for (int e = 0; e < 4; ++e) { a[e] = f2bf(a0[e]); a[4 + e] = f2bf(a1[e]); }

      #pragma unroll
      for (int f = 0; f < 4; ++f) {
        bf16x8 b = *(const bf16x8*)&Yb[yoff[f][j]];
        acc[f] = __builtin_amdgcn_mfma_f32_32x32x16_bf16(a, b, acc[f], 0, 0, 0);
      }
    }

    __builtin_amdgcn_sched_barrier(0);
    __builtin_amdgcn_s_barrier();
    __builtin_amdgcn_sched_barrier(0);
    if (s + 2 < 32) STAGE(s & 1, s + 2);
  }
#undef STAGE

  deg += __shfl_xor(deg, 32);
  if (l < 32)
    degpart[(size_t)ks * NN + R0 + wbase + l] = deg;

  // partial C tile (plain stores -> land in this XCD's L2; wbl2 flushes)
  short* pb = part + (size_t)ks * NN * DD + (size_t)(R0 + wbase) * DD;
  #pragma unroll
  for (int f = 0; f < 4; ++f)
    #pragma unroll
    for (int r = 0; r < 16; ++r) {
      const int row = (r & 3) + 8 * (r >> 2) + 4 * hi;
      pb[(size_t)row * DD + f * 32 + l31] = f2bf(acc[f][r]);
    }

  // ---- fused cross-slice reduction ----
  __syncthreads();                  // all block stores drained (vmcnt 0/thread)
  if (tid == 0) {
    __threadfence();                // release: L2 writeback -> device visible
    __hip_atomic_fetch_add(&cnt[mg], 1u, __ATOMIC_RELEASE,
                           __HIP_MEMORY_SCOPE_AGENT);
    while (__hip_atomic_load(&cnt[mg], __ATOMIC_ACQUIRE,
                             __HIP_MEMORY_SCOPE_AGENT) < 8u)
      __builtin_amdgcn_s_sleep(8);
  }
  __syncthreads();
  __threadfence();                  // acquire: invalidate stale cached lines

  // finish rows [R0 + ks*32, +32): 512 thr = 32 rows x 16 col-groups of 8
  const int frow = R0 + ks * 32 + (tid >> 4);
  const int fcol = (tid & 15) * 8;
  float s8[8];
  #pragma unroll
  for (int e = 0; e < 8; ++e) s8[e] = 0.f;
  float dsum = 0.f;
  #pragma unroll
  for (int q = 0; q < 8; ++q) {
    bf16x8 v = *(const bf16x8*)(part + (size_t)q * NN * DD
                                     + (size_t)frow * DD + fcol);
    #pragma unroll
    for (int e = 0; e < 8; ++e) s8[e] += bf2f(v[e]);
    dsum += degpart[(size_t)q * NN + frow];
  }
  f32x4 o0, o1;
  #pragma unroll
  for (int e = 0; e < 4; ++e) { o0[e] = s8[e] / dsum; o1[e] = s8[4 + e] / dsum; }
  *(f32x4*)(out + (size_t)frow * DD + fcol)     = o0;
  *(f32x4*)(out + (size_t)frow * DD + fcol + 4) = o1;
}

__global__ __launch_bounds__(512, 4) void gcn_main(
    const float* __restrict__ A, const short* __restrict__ yT,
    short* __restrict__ part, float* __restrict__ degpart,
    float* __restrict__ out, unsigned* __restrict__ cnt)
{
  __shared__ float Abuf[2][256 * 32];   // 2 x 32 KB
  __shared__ short Ybuf[2][128 * 32];   // 2 x  8 KB
  const int mg = blockIdx.x >> 3;
  if (mg & 1) gcn_body<2>(A, yT, part, degpart, out, cnt, Abuf, Ybuf); // NT
  else        gcn_body<0>(A, yT, part, degpart, out, cnt, Abuf, Ybuf); // cached
}

extern "C" void kernel_launch(void* const* d_in, const int* in_sizes, int n_in,
                              void* d_out, int out_size, void* d_ws, size_t ws_size,
                              hipStream_t stream) {
  const float* x = (const float*)d_in[0];   // [8192,128] fp32
  const float* A = (const float*)d_in[1];   // [8192,8192] fp32
  const float* W = (const float*)d_in[2];   // [128,128] fp32
  float* out = (float*)d_out;               // [8192,128] fp32

  char* ws = (char*)d_ws;
  short*    yT      = (short*)ws;                               // 2 MB bf16
  short*    part    = (short*)(ws + (2u << 20));                // 16 MB bf16 [8][8192][128]
  float*    degpart = (float*)(ws + (2u << 20) + (16u << 20));  // 256 KB fp32 [8][8192]
  unsigned* cnt     = (unsigned*)(ws + (2u << 20) + (16u << 20) + (256u << 10)); // 128 B

  hipMemsetAsync(cnt, 0, 32 * sizeof(unsigned), stream);
  xw_kernel<<<256, 256, 0, stream>>>(x, W, yT);
  gcn_main<<<256, 512, 0, stream>>>(A, yT, part, degpart, out, cnt);
}

// Round 14
// 85.474 us; speedup vs baseline: 2.0100x; 2.0064x over previous
//
#include <hip/hip_runtime.h>
#include <hip/hip_bf16.h>

#define NN 8192
#define DD 128

typedef __attribute__((ext_vector_type(4))) float f32x4;
typedef __attribute__((ext_vector_type(16))) float f32x16;
typedef __attribute__((ext_vector_type(8))) short bf16x8;
typedef __attribute__((ext_vector_type(4))) short s16x4;

__device__ __forceinline__ short f2bf(float f) {
  __hip_bfloat16 h = __float2bfloat16(f);
  return __builtin_bit_cast(short, h);
}
__device__ __forceinline__ float bf2f(short s) {
  unsigned u = ((unsigned)(unsigned short)s) << 16;
  return __builtin_bit_cast(float, u);
}

// async global->LDS, 16B/lane. AUX: 0 = cached, 2 = NT (no-allocate).
template <int AUX>
__device__ __forceinline__ void async_copy16(void* lds, const void* g) {
  __builtin_amdgcn_global_load_lds(
      (const __attribute__((address_space(1))) void*)g,
      (__attribute__((address_space(3))) void*)lds, 16, 0, AUX);
}

// ---------------------------------------------------------------------------
// Kernel 1: yT[n][k] = sum_d x[k][d] * W[d][n]   (bf16, transposed)
// ---------------------------------------------------------------------------
__global__ __launch_bounds__(256) void xw_kernel(
    const float* __restrict__ x, const float* __restrict__ W,
    short* __restrict__ yT)
{
  __shared__ float xs[32][129];
  __shared__ float Ws[128 * 128];
  const int t  = threadIdx.x;
  const int k0 = blockIdx.x * 32;

  #pragma unroll
  for (int i = 0; i < 16; ++i) {
    int idx = (i * 256 + t) * 4;
    *(f32x4*)&Ws[idx] = *(const f32x4*)(W + idx);
  }
  #pragma unroll
  for (int i = 0; i < 4; ++i) {
    int idx = i * 256 + t;
    int row = idx >> 5;
    int c4  = (idx & 31) * 4;
    f32x4 v = *(const f32x4*)(x + (size_t)(k0 + row) * DD + c4);
    xs[row][c4 + 0] = v[0]; xs[row][c4 + 1] = v[1];
    xs[row][c4 + 2] = v[2]; xs[row][c4 + 3] = v[3];
  }
  __syncthreads();

  const int kl = t & 31;
  const int g  = t >> 5;
  float acc[16];
  #pragma unroll
  for (int j = 0; j < 16; ++j) acc[j] = 0.f;

  for (int d = 0; d < 128; ++d) {
    float xv = xs[kl][d];
    const float* wr = &Ws[d * 128 + g * 16];
    f32x4 w0 = *(const f32x4*)(wr);
    f32x4 w1 = *(const f32x4*)(wr + 4);
    f32x4 w2 = *(const f32x4*)(wr + 8);
    f32x4 w3 = *(const f32x4*)(wr + 12);
    #pragma unroll
    for (int j = 0; j < 4; ++j) {
      acc[j]      += xv * w0[j];
      acc[4 + j]  += xv * w1[j];
      acc[8 + j]  += xv * w2[j];
      acc[12 + j] += xv * w3[j];
    }
  }
  #pragma unroll
  for (int j = 0; j < 16; ++j) {
    int n = g * 16 + j;
    yT[(size_t)n * NN + k0 + kl] = f2bf(acc[j]);
  }
}

// ---------------------------------------------------------------------------
// Kernel 2 (R11 config, best measured 85.4us total):
//   part[ks][m][n] = bf16(sum_{k in 1024-slice} A[m][k] y[k][n])
//   degpart[ks][m] = fp32 row-sum of the slice
// 256 blocks = 32 mg x 8 ks (ks = b&7 == XCD -> 256KB Y slice L2-resident).
// Block: 512 thr / 8 waves; wave owns 32 rows; MFMA 32x32x16; K-step 32;
// LDS 80KB dbuf -> 2 blocks/CU. DMA staging 5 instr/wave/step, vmcnt(5)
// pacing, raw barriers (prefetch stays in flight across them).
// A-policy: odd mg bands NT (stream, no L3 alloc), even bands cached ->
// even half (128MB) stays L3-resident across graph replays.
// Swizzle rule 21: linear LDS dest; source pre-XOR + read-side XOR.
// ---------------------------------------------------------------------------
template <int ANT>
__device__ __forceinline__ void gcn_body(
    const float* __restrict__ A, const short* __restrict__ yT,
    short* __restrict__ part, float* __restrict__ degpart,
    float (&Abuf)[2][256 * 32], short (&Ybuf)[2][128 * 32])
{
  const int tid = threadIdx.x;
  const int l   = tid & 63;
  const int w   = tid >> 6;            // wave 0..7
  const int ks  = blockIdx.x & 7;      // k-slice == XCD id
  const int mg  = blockIdx.x >> 3;     // 0..31
  const int R0  = mg * 256;
  const int kb  = ks * 1024;
  const int l31 = l & 31;
  const int hi  = l >> 5;
  const int wbase = w * 32;

  // staging sources (pre-swizzled)
  const int a_rin  = l >> 3;
  const int a_slot = l & 7;
  const float* gA[4];
  #pragma unroll
  for (int i = 0; i < 4; ++i) {
    const int r = wbase + 8 * i + a_rin;
    gA[i] = A + (size_t)(R0 + r) * NN + kb + ((a_slot ^ (r & 7)) << 2);
  }
  const int y_row = w * 16 + (l >> 2);
  const short* gY = yT + (size_t)y_row * NN + kb + (((l & 3) ^ (y_row & 3)) << 3);

  // read-side offsets
  const int arx = l31 & 7;
  int aoff[2][2];
  #pragma unroll
  for (int j = 0; j < 2; ++j)
    #pragma unroll
    for (int q = 0; q < 2; ++q)
      aoff[j][q] = (wbase + l31) * 32 + (((4 * j + 2 * hi + q) ^ arx) << 2);
  int yoff[4][2];
  #pragma unroll
  for (int f = 0; f < 4; ++f)
    #pragma unroll
    for (int j = 0; j < 2; ++j)
      yoff[f][j] = (f * 32 + l31) * 32 + (((2 * j + hi) ^ (l31 & 3)) << 3);

  f32x16 acc[4];
  #pragma unroll
  for (int f = 0; f < 4; ++f) acc[f] = (f32x16)0.f;
  float deg = 0.f;

#define STAGE(buf, step) do {                                              \
    const int _k = (step) * 32;                                            \
    _Pragma("unroll")                                                      \
    for (int _i = 0; _i < 4; ++_i)                                         \
      async_copy16<ANT>(&Abuf[buf][(wbase + 8 * _i) * 32], gA[_i] + _k);   \
    async_copy16<0>(&Ybuf[buf][w * 512], gY + _k);                         \
  } while (0)

  STAGE(0, 0);
  STAGE(1, 1);

  for (int s = 0; s < 32; ++s) {
    __builtin_amdgcn_sched_barrier(0);
    if (s < 31) asm volatile("s_waitcnt vmcnt(5)" ::: "memory");
    else        asm volatile("s_waitcnt vmcnt(0)" ::: "memory");
    __builtin_amdgcn_sched_barrier(0);
    __builtin_amdgcn_s_barrier();
    __builtin_amdgcn_sched_barrier(0);

    const float* Ab = &Abuf[s & 1][0];
    const short* Yb = &Ybuf[s & 1][0];

    #pragma unroll
    for (int j = 0; j < 2; ++j) {
      f32x4 a0 = *(const f32x4*)&Ab[aoff[j][0]];
      f32x4 a1 = *(const f32x4*)&Ab[aoff[j][1]];

      deg += (a0[0] + a0[1]) + (a0[2] + a0[3])
           + (a1[0] + a1[1]) + (a1[2] + a1[3]);

      bf16x8 a;
      #pragma unroll
      for (int e = 0; e < 4; ++e) { a[e] = f2bf(a0[e]); a[4 + e] = f2bf(a1[e]); }

      #pragma unroll
      for (int f = 0; f < 4; ++f) {
        bf16x8 b = *(const bf16x8*)&Yb[yoff[f][j]];
        acc[f] = __builtin_amdgcn_mfma_f32_32x32x16_bf16(a, b, acc[f], 0, 0, 0);
      }
    }

    __builtin_amdgcn_sched_barrier(0);
    __builtin_amdgcn_s_barrier();
    __builtin_amdgcn_sched_barrier(0);
    if (s + 2 < 32) STAGE(s & 1, s + 2);
  }
#undef STAGE

  deg += __shfl_xor(deg, 32);
  if (l < 32)
    degpart[(size_t)ks * NN + R0 + wbase + l] = deg;

  short* pb = part + (size_t)ks * NN * DD + (size_t)(R0 + wbase) * DD;
  #pragma unroll
  for (int f = 0; f < 4; ++f)
    #pragma unroll
    for (int r = 0; r < 16; ++r) {
      const int row = (r & 3) + 8 * (r >> 2) + 4 * hi;
      __builtin_nontemporal_store(f2bf(acc[f][r]),
          pb + (size_t)row * DD + f * 32 + l31);
    }
}

__global__ __launch_bounds__(512, 4) void gcn_main(
    const float* __restrict__ A, const short* __restrict__ yT,
    short* __restrict__ part, float* __restrict__ degpart)
{
  __shared__ float Abuf[2][256 * 32];   // 2 x 32 KB
  __shared__ short Ybuf[2][128 * 32];   // 2 x  8 KB
  const int mg = blockIdx.x >> 3;
  if (mg & 1) gcn_body<2>(A, yT, part, degpart, Abuf, Ybuf);  // NT (stream)
  else        gcn_body<0>(A, yT, part, degpart, Abuf, Ybuf);  // cached (pin)
}

// ---------------------------------------------------------------------------
// Kernel 3: out[m][n] = (sum_ks part[ks][m][n]) / (sum_ks degpart[ks][m])
// ---------------------------------------------------------------------------
__global__ __launch_bounds__(256) void reduce_kernel(
    const short* __restrict__ part, const float* __restrict__ degpart,
    float* __restrict__ out)
{
  const int idx = blockIdx.x * 256 + threadIdx.x;
  const int m   = idx >> 5;
  const int c4  = (idx & 31) * 4;

  float s0 = 0.f, s1 = 0.f, s2 = 0.f, s3 = 0.f, d = 0.f;
  #pragma unroll
  for (int ks = 0; ks < 8; ++ks) {
    s16x4 v = *(const s16x4*)(part + (size_t)ks * NN * DD + (size_t)m * DD + c4);
    s0 += bf2f(v[0]); s1 += bf2f(v[1]); s2 += bf2f(v[2]); s3 += bf2f(v[3]);
    d += degpart[(size_t)ks * NN + m];
  }
  f32x4 r;
  r[0] = s0 / d; r[1] = s1 / d; r[2] = s2 / d; r[3] = s3 / d;
  *(f32x4*)(out + (size_t)m * DD + c4) = r;
}

extern "C" void kernel_launch(void* const* d_in, const int* in_sizes, int n_in,
                              void* d_out, int out_size, void* d_ws, size_t ws_size,
                              hipStream_t stream) {
  const float* x = (const float*)d_in[0];   // [8192,128] fp32
  const float* A = (const float*)d_in[1];   // [8192,8192] fp32
  const float* W = (const float*)d_in[2];   // [128,128] fp32
  float* out = (float*)d_out;               // [8192,128] fp32

  char* ws = (char*)d_ws;
  short* yT      = (short*)ws;                              // 2 MB  bf16 [128][8192]
  short* part    = (short*)(ws + (2u << 20));               // 16 MB bf16 [8][8192][128]
  float* degpart = (float*)(ws + (2u << 20) + (16u << 20)); // 256 KB fp32 [8][8192]

  xw_kernel<<<256, 256, 0, stream>>>(x, W, yT);
  gcn_main<<<256, 512, 0, stream>>>(A, yT, part, degpart);
  reduce_kernel<<<1024, 256, 0, stream>>>(part, degpart, out);
}